// Round 17
// baseline (203.204 us; speedup 1.0000x reference)
//
#include <hip/hip_runtime.h>
#include <hip/hip_bf16.h>

#define NROWS 4096
#define TWO_N 8192
#define DDIM 64
#define INV_T 20.0f
// exp(dot*INV_T) = 2^(dot*INV_T*log2e); fold sqrt of the scale into each operand
#define SCALE2 5.3716292f   // sqrt(20 * 1.4426950408889634)
#define NPANEL 64           // 8192 / 128

typedef short bf16x8 __attribute__((ext_vector_type(8)));
typedef float f32x4 __attribute__((ext_vector_type(4)));

__device__ __forceinline__ unsigned short f32_to_bf16_rne(float f) {
    unsigned int u = __float_as_uint(f);
    return (unsigned short)((u + 0x7fffu + ((u >> 16) & 1u)) >> 16);
}

__device__ __forceinline__ float fast_exp2(float x) {
    float r;
    asm("v_exp_f32 %0, %1" : "=v"(r) : "v"(x));
    return r;
}

// Fast grid barrier: generation-based, one atomic arrival per block, s_sleep spin.
// cnt/sense zeroed via hipMemsetAsync before launch. Device-scope semantics:
// release = threadfence + (last) agent-scope store; acquire = agent-scope load.
__device__ __forceinline__ void grid_barrier(int* cnt, int* sense, int G, int gen) {
    __syncthreads();
    if (threadIdx.x == 0) {
        __threadfence();   // flush this XCD's prior writes device-visible
        if (atomicAdd(cnt, 1) == G - 1) {
            __hip_atomic_store(cnt, 0, __ATOMIC_RELAXED, __HIP_MEMORY_SCOPE_AGENT);
            __threadfence();
            __hip_atomic_store(sense, gen, __ATOMIC_RELEASE, __HIP_MEMORY_SCOPE_AGENT);
        } else {
            while (__hip_atomic_load(sense, __ATOMIC_ACQUIRE, __HIP_MEMORY_SCOPE_AGENT) < gen)
                __builtin_amdgcn_s_sleep(1);
        }
    }
    __syncthreads();
}

// featsT fragment-major layout: element (row=16g+lr, col=kb*32+lk*8+e) at
//   featsT[g*1024 + kb*512 + (lk*16+lr)*8 + e]
// NgP[k][i]: for row i in panel p, slot k is written by exactly one tile-block:
// rows of (p,k) for k>=p, cols of (k,p) for k<p  ->  Ng[i] = sum_k NgP[k][i].

__global__ __launch_bounds__(512) void fused_kernel(const float* __restrict__ f1,
                                                    const float* __restrict__ f2,
                                                    const int* __restrict__ label,
                                                    unsigned short* __restrict__ featsT,
                                                    float* __restrict__ posdot,
                                                    float* __restrict__ NgP,
                                                    int* __restrict__ cntG,
                                                    int* __restrict__ barMem,
                                                    float* __restrict__ out) {
    const int tid = threadIdx.x;
    const int bid = blockIdx.x;
    const int G = gridDim.x;
    int* bcnt = barMem;
    int* bsense = barMem + 4;   // separate cacheline-ish; 16B memset covers both

    __shared__ float rowP[2][128];
    __shared__ float colP[4][128];
    __shared__ int cnt[16];
    __shared__ float red[8];

    // ================= Phase A: prep (+histogram, +zero out) =================
    if (bid == 0 && tid == 0) out[0] = 0.f;
    for (int t = bid * 512 + tid; t < NROWS * 16; t += G * 512) {
        int r = t >> 4;
        int q = t & 15;
        int j = r * DDIM + q * 4;
        float4 a = *reinterpret_cast<const float4*>(&f1[j]);
        float4 b = *reinterpret_cast<const float4*>(&f2[j]);
        float d = a.x * b.x + a.y * b.y + a.z * b.z + a.w * b.w;
        d += __shfl_xor(d, 1);
        d += __shfl_xor(d, 2);
        d += __shfl_xor(d, 4);
        d += __shfl_xor(d, 8);
        if (q == 0) posdot[r] = d * INV_T;
        ushort4 ua = make_ushort4(f32_to_bf16_rne(a.x * SCALE2), f32_to_bf16_rne(a.y * SCALE2),
                                  f32_to_bf16_rne(a.z * SCALE2), f32_to_bf16_rne(a.w * SCALE2));
        ushort4 ub = make_ushort4(f32_to_bf16_rne(b.x * SCALE2), f32_to_bf16_rne(b.y * SCALE2),
                                  f32_to_bf16_rne(b.z * SCALE2), f32_to_bf16_rne(b.w * SCALE2));
        int g1 = r >> 4;
        int lr2 = r & 15;
        int kb = q >> 3;
        int lk2 = (q & 7) >> 1;
        int e  = (q & 1) * 4;
        int off = g1 * 1024 + kb * 512 + (lk2 * 16 + lr2) * 8 + e;
        *reinterpret_cast<ushort4*>(&featsT[off]) = ua;                 // f1: groups 0..255
        *reinterpret_cast<ushort4*>(&featsT[off + 256 * 1024]) = ub;    // f2: groups 256..511
    }
    if (bid == 0) {
        if (tid < 16) cnt[tid] = 0;
        __syncthreads();
        for (int i = tid; i < NROWS; i += 512) atomicAdd(&cnt[label[i]], 1);
        __syncthreads();
        if (tid < 16) cntG[tid] = cnt[tid];
    }
    grid_barrier(bcnt, bsense, G, 1);

    // ================= Phase B: upper-triangle 128x128 tiles =================
    const int wid = tid >> 6;
    const int lane = tid & 63;
    const int lr = lane & 15;
    const int lk = lane >> 4;
    const int wm = wid >> 1;         // 0..3
    const int wn = wid & 1;          // 0..1

    for (int tile = bid; tile < NPANEL * NPANEL; tile += G) {
        const int pr = tile >> 6;
        const int pc = tile & 63;
        if (pc < pr) continue;
        const int rowBase = pr * 128 + wm * 32;
        const int colBase = pc * 128 + wn * 64;
        const int gr0 = rowBase >> 4;
        const int gc0 = colBase >> 4;

        f32x4 acc[2][4];
        f32x4 zero = {0.f, 0.f, 0.f, 0.f};
        #pragma unroll
        for (int m = 0; m < 2; ++m)
            #pragma unroll
            for (int n = 0; n < 4; ++n) acc[m][n] = zero;

        #pragma unroll
        for (int kb = 0; kb < 2; ++kb) {
            bf16x8 afr[2], bfr[4];
            #pragma unroll
            for (int m = 0; m < 2; ++m)
                afr[m] = *reinterpret_cast<const bf16x8*>(
                    &featsT[(gr0 + m) * 1024 + kb * 512 + lane * 8]);
            #pragma unroll
            for (int n = 0; n < 4; ++n)
                bfr[n] = *reinterpret_cast<const bf16x8*>(
                    &featsT[(gc0 + n) * 1024 + kb * 512 + lane * 8]);
            #pragma unroll
            for (int m = 0; m < 2; ++m)
                #pragma unroll
                for (int n = 0; n < 4; ++n)
                    acc[m][n] = __builtin_amdgcn_mfma_f32_16x16x32_bf16(afr[m], bfr[n], acc[m][n], 0, 0, 0);
        }

        int rl[2][4];
        #pragma unroll
        for (int m = 0; m < 2; ++m)
            #pragma unroll
            for (int r = 0; r < 4; ++r)
                rl[m][r] = label[(rowBase + m * 16 + lk * 4 + r) & (NROWS - 1)];
        int cl[4];
        #pragma unroll
        for (int n = 0; n < 4; ++n)
            cl[n] = label[(colBase + n * 16 + lr) & (NROWS - 1)];

        float rsum[2][4];
        float csum[4] = {0.f, 0.f, 0.f, 0.f};
        #pragma unroll
        for (int m = 0; m < 2; ++m)
            #pragma unroll
            for (int r = 0; r < 4; ++r) {
                int lab = rl[m][r];
                float s = 0.f;
                #pragma unroll
                for (int n = 0; n < 4; ++n) {
                    float e = fast_exp2(acc[m][n][r]);   // = exp(dot/T)
                    float me = (cl[n] != lab) ? e : 0.f;
                    s += me;
                    csum[n] += me;
                }
                rsum[m][r] = s;
            }

        #pragma unroll
        for (int m = 0; m < 2; ++m)
            #pragma unroll
            for (int r = 0; r < 4; ++r) {
                float v = rsum[m][r];
                v += __shfl_xor(v, 1);
                v += __shfl_xor(v, 2);
                v += __shfl_xor(v, 4);
                v += __shfl_xor(v, 8);
                if (lr == 0) rowP[wn][wm * 32 + m * 16 + lk * 4 + r] = v;
            }
        #pragma unroll
        for (int n = 0; n < 4; ++n) {
            float v = csum[n];
            v += __shfl_xor(v, 16);
            v += __shfl_xor(v, 32);
            if (lane < 16) colP[wm][wn * 64 + n * 16 + lr] = v;
        }
        __syncthreads();

        if (tid < 128) {
            NgP[pc * TWO_N + pr * 128 + tid] = rowP[0][tid] + rowP[1][tid];
        } else if (tid < 256 && pr < pc) {
            int c = tid - 128;
            NgP[pr * TWO_N + pc * 128 + c] = colP[0][c] + colP[1][c] + colP[2][c] + colP[3][c];
        }
        __syncthreads();
    }
    grid_barrier(bcnt, bsense, G, 2);

    // ================= Phase C: final loss =================
    if (bid < TWO_N / 512) {
        int i = bid * 512 + tid;
        float a0 = 0.f, a1 = 0.f, a2 = 0.f, a3 = 0.f;
        #pragma unroll
        for (int k = 0; k < NPANEL; k += 4) {
            a0 += NgP[(k + 0) * TWO_N + i];
            a1 += NgP[(k + 1) * TWO_N + i];
            a2 += NgP[(k + 2) * TWO_N + i];
            a3 += NgP[(k + 3) * TWO_N + i];
        }
        float ng = (a0 + a1) + (a2 + a3);
        int base = i & (NROWS - 1);
        float pd = posdot[base];
        float gs = 2.0f * (float)cntG[label[base]];
        float s = (__logf(ng + __expf(pd)) - pd) / gs;

        #pragma unroll
        for (int m = 32; m; m >>= 1) s += __shfl_xor(s, m);
        if ((tid & 63) == 0) red[tid >> 6] = s;
        __syncthreads();
        if (tid == 0) {
            float tsum = 0.f;
            #pragma unroll
            for (int w = 0; w < 8; ++w) tsum += red[w];
            atomicAdd(out, tsum);
        }
    }
}

extern "C" void kernel_launch(void* const* d_in, const int* in_sizes, int n_in,
                              void* d_out, int out_size, void* d_ws, size_t ws_size,
                              hipStream_t stream) {
    const float* f1 = (const float*)d_in[0];
    const float* f2 = (const float*)d_in[1];
    const int* label = (const int*)d_in[2];
    float* out = (float*)d_out;

    char* ws = (char*)d_ws;
    unsigned short* featsT = (unsigned short*)ws;                    // 1 MB
    float* NgP    = (float*)(ws + (1u << 20));                       // 2 MB
    float* posdot = (float*)(ws + (3u << 20));                       // 32 KB
    int* cntG     = (int*)(ws + (3u << 20) + 32768);                 // 64 B
    int* barMem   = (int*)(ws + (4u << 20));                         // 32 B (cnt @+0, sense @+16)

    // zero barrier state (cnt, sense) — stream-ordered before the kernel
    hipMemsetAsync(barMem, 0, 32, stream);

    int nb = 0;
    hipOccupancyMaxActiveBlocksPerMultiprocessor(&nb, fused_kernel, 512, 0);
    if (nb < 1) nb = 1;
    int G = nb * 256;                 // 256 CUs on MI355X
    if (G > 512) G = 512;
    if (G < 256) G = 256;

    void* args[] = {(void*)&f1, (void*)&f2, (void*)&label, (void*)&featsT,
                    (void*)&posdot, (void*)&NgP, (void*)&cntG, (void*)&barMem, (void*)&out};
    hipLaunchCooperativeKernel(fused_kernel, dim3(G), dim3(512), args, 0, stream);
}